// Round 2
// baseline (1751.401 us; speedup 1.0000x reference)
//
#include <hip/hip_runtime.h>

#define B 8
#define N 8192
#define E 65536
#define FIN 64
#define H 128
#define OUTD 256
#define NLAYER 3
#define EPS 1e-5f
#define PCHUNK 64          // pooling chunks per batch
#define PNODES (N / PCHUNK)

// ---------------- Kernel 1: x = relu(feats @ in_W + in_b) ----------------
// grid: B*N blocks, H threads.
__global__ void k_in_proj(const float* __restrict__ feats,
                          const float* __restrict__ W,
                          const float* __restrict__ bias,
                          float* __restrict__ x) {
    const int node = blockIdx.x;            // b*N + n
    const int h = threadIdx.x;              // 0..H-1
    __shared__ float f[FIN];
    if (h < FIN) f[h] = feats[(size_t)node * FIN + h];
    __syncthreads();
    float acc = bias[h];
    #pragma unroll
    for (int k = 0; k < FIN; ++k)
        acc = fmaf(f[k], W[k * H + h], acc);
    x[(size_t)node * H + h] = fmaxf(acc, 0.f);
}

// ---------------- Kernel 2: edge scatter (segment mean numerators) ----------------
__global__ void k_scatter(const float* __restrict__ x,
                          const int* __restrict__ ei,
                          const float* __restrict__ emask,
                          float* __restrict__ agg,
                          float* __restrict__ cnt) {
    const long long idx = (long long)blockIdx.x * blockDim.x + threadIdx.x; // b*E*H range
    const int h = (int)(idx & (H - 1));
    const long long eg = idx >> 7;          // b*E + e
    const int b = (int)(eg >> 16);          // E = 2^16
    const int e = (int)(eg & (E - 1));
    const float m = emask[eg];
    if (m > 0.f) {
        const int src = ei[((long long)b * 2) * E + e];
        const int tgt = ei[((long long)b * 2 + 1) * E + e];
        const float v = x[((long long)b * N + src) * H + h] * m;
        atomicAdd(&agg[((long long)b * N + tgt) * H + h], v);
        if (h == 0) atomicAdd(&cnt[(long long)b * N + tgt], m);
    }
}

// ---------------- Kernel 3: fused layer: dual GEMM + relu + layernorm + mask ----------------
// grid: B*N blocks, H threads (thread h owns output channel h).
__global__ void k_layer(const float* __restrict__ x,
                        const float* __restrict__ agg,
                        const float* __restrict__ cnt,
                        const float* __restrict__ sW,
                        const float* __restrict__ sb,
                        const float* __restrict__ nW,
                        const float* __restrict__ nb,
                        const float* __restrict__ lng,
                        const float* __restrict__ lnb,
                        const float* __restrict__ nmask,
                        float* __restrict__ xo) {
    const int node = blockIdx.x;            // b*N + n
    const int h = threadIdx.x;
    __shared__ float xs[H];
    __shared__ float ns[H];
    __shared__ float red[H];

    const float inv = 1.f / fmaxf(cnt[node], 1.f);
    xs[h] = x[(size_t)node * H + h];
    ns[h] = agg[(size_t)node * H + h] * inv;
    __syncthreads();

    float acc = sb[h] + nb[h];
    #pragma unroll 8
    for (int k = 0; k < H; ++k)
        acc += xs[k] * sW[k * H + h] + ns[k] * nW[k * H + h];
    acc = fmaxf(acc, 0.f);

    // mean
    red[h] = acc;
    __syncthreads();
    #pragma unroll
    for (int s = H / 2; s > 0; s >>= 1) {
        if (h < s) red[h] += red[h + s];
        __syncthreads();
    }
    const float mu = red[0] * (1.f / H);
    __syncthreads();
    // variance
    const float d = acc - mu;
    red[h] = d * d;
    __syncthreads();
    #pragma unroll
    for (int s = H / 2; s > 0; s >>= 1) {
        if (h < s) red[h] += red[h + s];
        __syncthreads();
    }
    const float var = red[0] * (1.f / H);

    const float y = d * rsqrtf(var + EPS) * lng[h] + lnb[h];
    xo[(size_t)node * H + h] = y * nmask[node];
}

// ---------------- Kernel 4a: pooling partials ----------------
// grid: (B, PCHUNK) blocks, H threads. partial layout per (b,c): [sum H][max H][nv]
__global__ void k_pool1(const float* __restrict__ x,
                        const float* __restrict__ nmask,
                        float* __restrict__ part) {
    const int b = blockIdx.x, c = blockIdx.y, h = threadIdx.x;
    const int n0 = c * PNODES;
    float s = 0.f, mx = -INFINITY, nv = 0.f;
    for (int i = 0; i < PNODES; ++i) {
        const int n = n0 + i;
        const float m = nmask[b * N + n];
        const float v = x[((size_t)b * N + n) * H + h] * m;
        s += v;
        if (m > 0.f) mx = fmaxf(mx, v);
        nv += m;
    }
    float* p = part + ((size_t)b * PCHUNK + c) * (2 * H + 1);
    p[h] = s;
    p[H + h] = mx;
    if (h == 0) p[2 * H] = nv;
}

// ---------------- Kernel 4b: pooling reduce ----------------
// grid: B blocks, H threads.
__global__ void k_pool2(const float* __restrict__ part,
                        float* __restrict__ pool) {
    const int b = blockIdx.x, h = threadIdx.x;
    float s = 0.f, mx = -INFINITY, nv = 0.f;
    for (int c = 0; c < PCHUNK; ++c) {
        const float* p = part + ((size_t)b * PCHUNK + c) * (2 * H + 1);
        s += p[h];
        mx = fmaxf(mx, p[H + h]);
        nv += p[2 * H];
    }
    pool[(size_t)b * 2 * H + h] = s / fmaxf(nv, 1.f);
    pool[(size_t)b * 2 * H + H + h] = mx;
}

// ---------------- Kernel 5: MLP head ----------------
// grid: B blocks, OUTD threads.
__global__ void k_head(const float* __restrict__ pool,
                       const float* __restrict__ W1,
                       const float* __restrict__ b1,
                       const float* __restrict__ W2,
                       const float* __restrict__ b2,
                       float* __restrict__ out) {
    const int b = blockIdx.x, t = threadIdx.x;
    __shared__ float g[2 * H];
    __shared__ float hid[H];
    if (t < 2 * H) g[t] = pool[(size_t)b * 2 * H + t];
    __syncthreads();
    if (t < H) {
        float a = b1[t];
        #pragma unroll 8
        for (int k = 0; k < 2 * H; ++k)
            a = fmaf(g[k], W1[k * H + t], a);
        hid[t] = fmaxf(a, 0.f);
    }
    __syncthreads();
    float a = b2[t];
    #pragma unroll 8
    for (int k = 0; k < H; ++k)
        a = fmaf(hid[k], W2[k * OUTD + t], a);
    out[(size_t)b * OUTD + t] = a;
}

extern "C" void kernel_launch(void* const* d_in, const int* in_sizes, int n_in,
                              void* d_out, int out_size, void* d_ws, size_t ws_size,
                              hipStream_t stream) {
    const float* feats = (const float*)d_in[0];
    const int*   ei    = (const int*)d_in[1];
    const float* nmask = (const float*)d_in[2];
    const float* emask = (const float*)d_in[3];
    const float* inW   = (const float*)d_in[4];
    const float* inb   = (const float*)d_in[5];
    const float* selfW = (const float*)d_in[6];
    const float* selfb = (const float*)d_in[7];
    const float* neighW= (const float*)d_in[8];
    const float* neighb= (const float*)d_in[9];
    const float* lng   = (const float*)d_in[10];
    const float* lnb   = (const float*)d_in[11];
    const float* W1    = (const float*)d_in[12];
    const float* b1    = (const float*)d_in[13];
    const float* W2    = (const float*)d_in[14];
    const float* b2    = (const float*)d_in[15];
    float* out = (float*)d_out;

    // workspace layout (f32)
    const size_t nxh = (size_t)B * N * H;      // 8.4M floats
    float* xA   = (float*)d_ws;
    float* xB   = xA + nxh;
    float* agg  = xB + nxh;
    float* cnt  = agg + nxh;                   // B*N, contiguous after agg
    float* part = cnt + (size_t)B * N;
    float* pool = part + (size_t)B * PCHUNK * (2 * H + 1);

    k_in_proj<<<B * N, H, 0, stream>>>(feats, inW, inb, xA);

    float* xin = xA;
    float* xout = xB;
    for (int l = 0; l < NLAYER; ++l) {
        // zero agg (B*N*H) and cnt (B*N) in one contiguous memset
        hipMemsetAsync(agg, 0, (nxh + (size_t)B * N) * sizeof(float), stream);
        const long long nthreads = (long long)B * E * H;
        k_scatter<<<(int)(nthreads / 256), 256, 0, stream>>>(xin, ei, emask, agg, cnt);
        k_layer<<<B * N, H, 0, stream>>>(xin, agg, cnt,
                                         selfW + (size_t)l * H * H, selfb + (size_t)l * H,
                                         neighW + (size_t)l * H * H, neighb + (size_t)l * H,
                                         lng + (size_t)l * H, lnb + (size_t)l * H,
                                         nmask, xout);
        float* tmp = xin; xin = xout; xout = tmp;
    }

    k_pool1<<<dim3(B, PCHUNK), H, 0, stream>>>(xin, nmask, part);
    k_pool2<<<B, H, 0, stream>>>(part, pool);
    k_head<<<B, OUTD, 0, stream>>>(pool, W1, b1, W2, b2, out);
}

// Round 3
// 763.628 us; speedup vs baseline: 2.2935x; 2.2935x over previous
//
#include <hip/hip_runtime.h>

#define B 8
#define N 8192
#define E 65536
#define FIN 64
#define H 128
#define OUTD 256
#define NLAYER 3
#define EPS 1e-5f
#define PCHUNK 64
#define PNODES (N / PCHUNK)
#define TM 32            // nodes per block in GEMM kernels
#define PADK 132         // LDS pitch for 128-float rows (multiple of 4, breaks bank stride)
#define PADF 68          // LDS pitch for 64-float rows

// ---------------- input projection: x = relu(feats @ in_W + b), tiled ----------------
// grid: B*N/TM blocks, 256 threads (8 node-groups x 32 h-groups), 4x4 regs/thread
__global__ __launch_bounds__(256) void k_inproj2(const float* __restrict__ feats,
                                                 const float* __restrict__ W,
                                                 const float* __restrict__ bias,
                                                 float* __restrict__ x) {
    __shared__ float fs[TM * PADF];      // 32 rows x 64 k
    __shared__ float wB[FIN * H];        // full weight, 32 KB
    const int tid = threadIdx.x;
    const int i = tid >> 5, j = tid & 31;
    const int row0 = blockIdx.x * TM;

    for (int v = tid; v < TM * (FIN / 4); v += 256) {   // 512 float4
        int n = v >> 4, kq = (v & 15) << 2;
        *(float4*)&fs[n * PADF + kq] = *(const float4*)&feats[(size_t)(row0 + n) * FIN + kq];
    }
    for (int v = tid; v < FIN * H / 4; v += 256)        // 2048 float4
        *(float4*)&wB[v * 4] = *(const float4*)&W[v * 4];
    __syncthreads();

    float acc[4][4] = {};
    #pragma unroll
    for (int k4 = 0; k4 < FIN / 4; ++k4) {
        float4 xa[4];
        #pragma unroll
        for (int a = 0; a < 4; ++a)
            xa[a] = *(const float4*)&fs[(i * 4 + a) * PADF + k4 * 4];
        #pragma unroll
        for (int t = 0; t < 4; ++t) {
            float4 bs = *(const float4*)&wB[(k4 * 4 + t) * H + (j << 2)];
            #pragma unroll
            for (int a = 0; a < 4; ++a) {
                const float va = ((const float*)&xa[a])[t];
                acc[a][0] = fmaf(va, bs.x, acc[a][0]);
                acc[a][1] = fmaf(va, bs.y, acc[a][1]);
                acc[a][2] = fmaf(va, bs.z, acc[a][2]);
                acc[a][3] = fmaf(va, bs.w, acc[a][3]);
            }
        }
    }
    const float4 bv = *(const float4*)&bias[j << 2];
    #pragma unroll
    for (int a = 0; a < 4; ++a) {
        float4 o;
        o.x = fmaxf(acc[a][0] + bv.x, 0.f);
        o.y = fmaxf(acc[a][1] + bv.y, 0.f);
        o.z = fmaxf(acc[a][2] + bv.z, 0.f);
        o.w = fmaxf(acc[a][3] + bv.w, 0.f);
        *(float4*)&x[(size_t)(row0 + i * 4 + a) * H + (j << 2)] = o;
    }
}

// ---------------- CSR build ----------------
__global__ void k_count(const int* __restrict__ ei, const float* __restrict__ emask,
                        int* __restrict__ cnt_i) {
    const int ge = blockIdx.x * 256 + threadIdx.x;      // b*E+e
    if (emask[ge] > 0.f) {
        const int b = ge >> 16, e = ge & 0xFFFF;
        const int tgt = ei[(b * 2 + 1) * E + e];
        atomicAdd(&cnt_i[b * N + tgt], 1);
    }
}

// single block, 1024 threads, scans 65536 counts -> off (exclusive), cur copy
__global__ __launch_bounds__(1024) void k_scan(const int* __restrict__ cnt_i,
                                               int* __restrict__ off, int* __restrict__ cur) {
    __shared__ int part[1024];
    const int t = threadIdx.x;
    const int base = t * 64;
    int s = 0;
    for (int u = 0; u < 64; ++u) s += cnt_i[base + u];
    part[t] = s;
    __syncthreads();
    for (int d = 1; d < 1024; d <<= 1) {
        int v = (t >= d) ? part[t - d] : 0;
        __syncthreads();
        part[t] += v;
        __syncthreads();
    }
    int pre = (t == 0) ? 0 : part[t - 1];
    for (int u = 0; u < 64; ++u) {
        const int c = cnt_i[base + u];
        off[base + u] = pre;
        cur[base + u] = pre;
        pre += c;
    }
    if (t == 1023) off[B * N] = pre;
}

__global__ void k_fill(const int* __restrict__ ei, const float* __restrict__ emask,
                       int* __restrict__ cur, int* __restrict__ eord) {
    const int ge = blockIdx.x * 256 + threadIdx.x;
    if (emask[ge] > 0.f) {
        const int b = ge >> 16, e = ge & 0xFFFF;
        const int tgt = ei[(b * 2 + 1) * E + e];
        const int p = atomicAdd(&cur[b * N + tgt], 1);
        eord[p] = ge;
    }
}

// ---------------- gather aggregation (no f32 atomics) ----------------
// grid: B*N blocks x 128 threads. agg[r] = sum(x[src]*m), cntv[r] = sum(m)
__global__ void k_gather(const float* __restrict__ x, const int* __restrict__ ei,
                         const float* __restrict__ emask, const int* __restrict__ off,
                         const int* __restrict__ eord,
                         float* __restrict__ agg, float* __restrict__ cntv) {
    const int r = blockIdx.x;
    const int h = threadIdx.x;
    const int b = r >> 13;               // N = 2^13
    const int j1 = off[r + 1];
    float acc = 0.f, c = 0.f;
    for (int j = off[r]; j < j1; ++j) {
        const int ge = eord[j];
        const int e = ge & 0xFFFF;
        const float m = emask[ge];
        const int src = ei[(b * 2) * E + e];
        acc = fmaf(x[((size_t)b * N + src) * H + h], m, acc);
        c += m;
    }
    agg[(size_t)r * H + h] = acc;
    if (h == 0) cntv[r] = c;
}

// ---------------- fused layer: tiled dual GEMM + bias + relu + LN + mask, in-place ----------------
__global__ __launch_bounds__(256) void k_layer2(const float* __restrict__ x,
                                                const float* __restrict__ agg,
                                                const float* __restrict__ cntv,
                                                const float* __restrict__ sW,
                                                const float* __restrict__ sb,
                                                const float* __restrict__ nW,
                                                const float* __restrict__ nb,
                                                const float* __restrict__ lng,
                                                const float* __restrict__ lnb,
                                                const float* __restrict__ nmask,
                                                float* __restrict__ xo) {
    __shared__ float xs[TM * PADK];     // x rows; reused as hpre after GEMM
    __shared__ float ns[TM * PADK];     // mean-aggregated rows
    __shared__ float wS[16 * H];
    __shared__ float wN[16 * H];
    __shared__ float red[TM * 8];
    __shared__ float mus[TM], isd[TM];

    const int tid = threadIdx.x;
    const int i = tid >> 5, j = tid & 31;
    const int row0 = blockIdx.x * TM;

    for (int v = tid; v < TM * 32; v += 256) {          // 1024 float4
        const int n = v >> 5;
        const int kq = (v & 31) << 2;
        *(float4*)&xs[n * PADK + kq] = *(const float4*)&x[(size_t)(row0 + n) * H + kq];
        const float inv = 1.f / fmaxf(cntv[row0 + n], 1.f);
        float4 av = *(const float4*)&agg[(size_t)(row0 + n) * H + kq];
        av.x *= inv; av.y *= inv; av.z *= inv; av.w *= inv;
        *(float4*)&ns[n * PADK + kq] = av;
    }

    float acc[4][4] = {};
    for (int kt = 0; kt < H / 16; ++kt) {
        __syncthreads();
        for (int v = tid; v < 512; v += 256) {          // 16x128 floats per weight
            *(float4*)&wS[v * 4] = *(const float4*)&sW[kt * 16 * H + v * 4];
            *(float4*)&wN[v * 4] = *(const float4*)&nW[kt * 16 * H + v * 4];
        }
        __syncthreads();
        #pragma unroll
        for (int k4 = 0; k4 < 4; ++k4) {
            float4 xa[4], na[4];
            #pragma unroll
            for (int a = 0; a < 4; ++a) {
                const int n = i * 4 + a;
                xa[a] = *(const float4*)&xs[n * PADK + kt * 16 + k4 * 4];
                na[a] = *(const float4*)&ns[n * PADK + kt * 16 + k4 * 4];
            }
            #pragma unroll
            for (int t = 0; t < 4; ++t) {
                const float4 bs = *(const float4*)&wS[(k4 * 4 + t) * H + (j << 2)];
                const float4 bn = *(const float4*)&wN[(k4 * 4 + t) * H + (j << 2)];
                #pragma unroll
                for (int a = 0; a < 4; ++a) {
                    const float va = ((const float*)&xa[a])[t];
                    const float vn = ((const float*)&na[a])[t];
                    acc[a][0] = fmaf(va, bs.x, fmaf(vn, bn.x, acc[a][0]));
                    acc[a][1] = fmaf(va, bs.y, fmaf(vn, bn.y, acc[a][1]));
                    acc[a][2] = fmaf(va, bs.z, fmaf(vn, bn.z, acc[a][2]));
                    acc[a][3] = fmaf(va, bs.w, fmaf(vn, bn.w, acc[a][3]));
                }
            }
        }
    }

    // bias + relu -> hpre (reuse xs)
    __syncthreads();
    {
        const int hb = j << 2;
        const float4 sbv = *(const float4*)&sb[hb];
        const float4 nbv = *(const float4*)&nb[hb];
        #pragma unroll
        for (int a = 0; a < 4; ++a) {
            const int n = i * 4 + a;
            xs[n * PADK + hb + 0] = fmaxf(acc[a][0] + sbv.x + nbv.x, 0.f);
            xs[n * PADK + hb + 1] = fmaxf(acc[a][1] + sbv.y + nbv.y, 0.f);
            xs[n * PADK + hb + 2] = fmaxf(acc[a][2] + sbv.z + nbv.z, 0.f);
            xs[n * PADK + hb + 3] = fmaxf(acc[a][3] + sbv.w + nbv.w, 0.f);
        }
    }
    __syncthreads();

    // LN two-pass: 8 threads per node, 16 values each
    const int node = tid >> 3, seg = tid & 7;
    {
        float s = 0.f;
        #pragma unroll
        for (int u = 0; u < 16; ++u) s += xs[node * PADK + seg * 16 + u];
        red[node * 8 + seg] = s;
    }
    __syncthreads();
    if (tid < TM) {
        float s = 0.f;
        #pragma unroll
        for (int u = 0; u < 8; ++u) s += red[tid * 8 + u];
        mus[tid] = s * (1.f / H);
    }
    __syncthreads();
    {
        const float mu = mus[node];
        float q = 0.f;
        #pragma unroll
        for (int u = 0; u < 16; ++u) {
            const float d = xs[node * PADK + seg * 16 + u] - mu;
            q = fmaf(d, d, q);
        }
        red[node * 8 + seg] = q;
    }
    __syncthreads();
    if (tid < TM) {
        float q = 0.f;
        #pragma unroll
        for (int u = 0; u < 8; ++u) q += red[tid * 8 + u];
        isd[tid] = rsqrtf(q * (1.f / H) + EPS);
    }
    __syncthreads();
    {
        const float mu = mus[node], sd = isd[node];
        const float m = nmask[row0 + node];
        const size_t gbase = (size_t)(row0 + node) * H + seg * 16;
        #pragma unroll
        for (int u4 = 0; u4 < 4; ++u4) {
            const int h = seg * 16 + u4 * 4;
            const float4 gv = *(const float4*)&lng[h];
            const float4 bv = *(const float4*)&lnb[h];
            float4 o;
            o.x = (fmaf(xs[node * PADK + h + 0] - mu, sd * gv.x, bv.x)) * m;
            o.y = (fmaf(xs[node * PADK + h + 1] - mu, sd * gv.y, bv.y)) * m;
            o.z = (fmaf(xs[node * PADK + h + 2] - mu, sd * gv.z, bv.z)) * m;
            o.w = (fmaf(xs[node * PADK + h + 3] - mu, sd * gv.w, bv.w)) * m;
            *(float4*)&xo[gbase + u4 * 4] = o;
        }
    }
}

// ---------------- pooling ----------------
__global__ void k_pool1(const float* __restrict__ x, const float* __restrict__ nmask,
                        float* __restrict__ part) {
    const int b = blockIdx.x, c = blockIdx.y, h = threadIdx.x;
    const int n0 = c * PNODES;
    float s = 0.f, mx = -INFINITY, nv = 0.f;
    for (int it = 0; it < PNODES; ++it) {
        const int n = n0 + it;
        const float m = nmask[b * N + n];
        const float v = x[((size_t)b * N + n) * H + h] * m;
        s += v;
        if (m > 0.f) mx = fmaxf(mx, v);
        nv += m;
    }
    float* p = part + ((size_t)b * PCHUNK + c) * (2 * H + 1);
    p[h] = s;
    p[H + h] = mx;
    if (h == 0) p[2 * H] = nv;
}

__global__ void k_pool2(const float* __restrict__ part, float* __restrict__ pool) {
    const int b = blockIdx.x, h = threadIdx.x;
    float s = 0.f, mx = -INFINITY, nv = 0.f;
    for (int c = 0; c < PCHUNK; ++c) {
        const float* p = part + ((size_t)b * PCHUNK + c) * (2 * H + 1);
        s += p[h];
        mx = fmaxf(mx, p[H + h]);
        nv += p[2 * H];
    }
    pool[(size_t)b * 2 * H + h] = s / fmaxf(nv, 1.f);
    pool[(size_t)b * 2 * H + H + h] = mx;
}

// ---------------- MLP head ----------------
__global__ void k_head(const float* __restrict__ pool,
                       const float* __restrict__ W1, const float* __restrict__ b1,
                       const float* __restrict__ W2, const float* __restrict__ b2,
                       float* __restrict__ out) {
    const int b = blockIdx.x, t = threadIdx.x;
    __shared__ float g[2 * H];
    __shared__ float hid[H];
    if (t < 2 * H) g[t] = pool[(size_t)b * 2 * H + t];
    __syncthreads();
    if (t < H) {
        float a = b1[t];
        #pragma unroll 8
        for (int k = 0; k < 2 * H; ++k) a = fmaf(g[k], W1[k * H + t], a);
        hid[t] = fmaxf(a, 0.f);
    }
    __syncthreads();
    float a = b2[t];
    #pragma unroll 8
    for (int k = 0; k < H; ++k) a = fmaf(hid[k], W2[k * OUTD + t], a);
    out[(size_t)b * OUTD + t] = a;
}

extern "C" void kernel_launch(void* const* d_in, const int* in_sizes, int n_in,
                              void* d_out, int out_size, void* d_ws, size_t ws_size,
                              hipStream_t stream) {
    const float* feats = (const float*)d_in[0];
    const int*   ei    = (const int*)d_in[1];
    const float* nmask = (const float*)d_in[2];
    const float* emask = (const float*)d_in[3];
    const float* inW   = (const float*)d_in[4];
    const float* inb   = (const float*)d_in[5];
    const float* selfW = (const float*)d_in[6];
    const float* selfb = (const float*)d_in[7];
    const float* neighW= (const float*)d_in[8];
    const float* neighb= (const float*)d_in[9];
    const float* lng   = (const float*)d_in[10];
    const float* lnb   = (const float*)d_in[11];
    const float* W1    = (const float*)d_in[12];
    const float* b1    = (const float*)d_in[13];
    const float* W2    = (const float*)d_in[14];
    const float* b2    = (const float*)d_in[15];
    float* out = (float*)d_out;

    // workspace layout
    const size_t nxh = (size_t)B * N * H;               // 8.4M floats
    float* xA   = (float*)d_ws;
    float* agg  = xA + nxh;
    float* cntv = agg + nxh;                            // B*N
    float* part = cntv + (size_t)B * N;
    float* pool = part + (size_t)B * PCHUNK * (2 * H + 1);
    int*   cnt_i = (int*)(pool + (size_t)B * 2 * H);
    int*   off   = cnt_i + (size_t)B * N;               // B*N+1
    int*   cur   = off + (size_t)B * N + 1;
    int*   eord  = cur + (size_t)B * N;                 // B*E

    // input projection
    k_inproj2<<<B * N / TM, 256, 0, stream>>>(feats, inW, inb, xA);

    // CSR build (once; edge structure shared by all layers)
    hipMemsetAsync(cnt_i, 0, (size_t)B * N * sizeof(int), stream);
    k_count<<<B * E / 256, 256, 0, stream>>>(ei, emask, cnt_i);
    k_scan<<<1, 1024, 0, stream>>>(cnt_i, off, cur);
    k_fill<<<B * E / 256, 256, 0, stream>>>(ei, emask, cur, eord);

    for (int l = 0; l < NLAYER; ++l) {
        k_gather<<<B * N, H, 0, stream>>>(xA, ei, emask, off, eord, agg, cntv);
        k_layer2<<<B * N / TM, 256, 0, stream>>>(xA, agg, cntv,
                                                 selfW + (size_t)l * H * H, selfb + (size_t)l * H,
                                                 neighW + (size_t)l * H * H, neighb + (size_t)l * H,
                                                 lng + (size_t)l * H, lnb + (size_t)l * H,
                                                 nmask, xA);
    }

    k_pool1<<<dim3(B, PCHUNK), H, 0, stream>>>(xA, nmask, part);
    k_pool2<<<B, H, 0, stream>>>(part, pool);
    k_head<<<B, OUTD, 0, stream>>>(pool, W1, b1, W2, b2, out);
}

// Round 4
// 487.890 us; speedup vs baseline: 3.5897x; 1.5652x over previous
//
#include <hip/hip_runtime.h>
#include <hip/hip_bf16.h>

#define B 8
#define N 8192
#define E 65536
#define FIN 64
#define H 128
#define OUTD 256
#define NLAYER 3
#define EPS 1e-5f
#define PCHUNK 64
#define PNODES (N / PCHUNK)
#define TM 32
#define PADF 68
#define NNODE (B * N)            // 65536 rows
#define KSTEPS 24                // 6 groups x 4 k-steps of K=32
#define BPL (KSTEPS * 8 * 512)   // Bp ushort elems per layer = 98304

typedef float f32x4 __attribute__((ext_vector_type(4)));
typedef __bf16 bf16x8 __attribute__((ext_vector_type(8)));

__device__ __forceinline__ float b2f(unsigned short u) {
    union { float f; unsigned int i; } c; c.i = ((unsigned int)u) << 16; return c.f;
}
__device__ __forceinline__ unsigned short f2b(float f) {
    __hip_bfloat16 h = __float2bfloat16(f);          // RTNE
    return *reinterpret_cast<unsigned short*>(&h);
}

// ---------------- weight pre-pack: fragment-ordered split-bf16 B' ----------------
// term order (groups of 4 k-steps): xh*sWhi, xl*sWhi, xh*sWlo, nh*nWhi, nl*nWhi, nh*nWlo
// Bp[((l*24+s)*8 + tile)*512 + lane*8 + j] = B[k = (s%4)*32 + (lane/16)*8 + j][n = tile*16 + lane%16]
__global__ void k_prepB(const float* __restrict__ selfW, const float* __restrict__ neighW,
                        unsigned short* __restrict__ Bp) {
    const int idx = blockIdx.x;            // l*24*8 + s*8 + t
    const int t = idx & 7;
    const int s = (idx >> 3) % KSTEPS;
    const int l = idx / (KSTEPS * 8);
    const int lane = threadIdx.x;
    const int quad = lane >> 4, col = lane & 15;
    const int g = s >> 2;
    const float* W = ((g < 3) ? selfW : neighW) + (size_t)l * H * H;
    const bool lo = (g == 2 || g == 5);
    const int n = t * 16 + col;
    unsigned short* dst = Bp + ((size_t)(l * KSTEPS + s) * 8 + t) * 512 + lane * 8;
    #pragma unroll
    for (int j = 0; j < 8; ++j) {
        const int kk = (s & 3) * 32 + quad * 8 + j;
        const float w = W[kk * H + n];
        const unsigned short hi = f2b(w);
        dst[j] = lo ? f2b(w - b2f(hi)) : hi;
    }
}

// ---------------- input projection -> split-bf16 x ----------------
__global__ __launch_bounds__(256) void k_inproj3(const float* __restrict__ feats,
                                                 const float* __restrict__ W,
                                                 const float* __restrict__ bias,
                                                 unsigned short* __restrict__ xh,
                                                 unsigned short* __restrict__ xl) {
    __shared__ float fs[TM * PADF];
    __shared__ float wB[FIN * H];
    const int tid = threadIdx.x;
    const int i = tid >> 5, j = tid & 31;
    const int row0 = blockIdx.x * TM;

    for (int v = tid; v < TM * (FIN / 4); v += 256) {
        int n = v >> 4, kq = (v & 15) << 2;
        *(float4*)&fs[n * PADF + kq] = *(const float4*)&feats[(size_t)(row0 + n) * FIN + kq];
    }
    for (int v = tid; v < FIN * H / 4; v += 256)
        *(float4*)&wB[v * 4] = *(const float4*)&W[v * 4];
    __syncthreads();

    float acc[4][4] = {};
    #pragma unroll
    for (int k4 = 0; k4 < FIN / 4; ++k4) {
        float4 xa[4];
        #pragma unroll
        for (int a = 0; a < 4; ++a)
            xa[a] = *(const float4*)&fs[(i * 4 + a) * PADF + k4 * 4];
        #pragma unroll
        for (int t = 0; t < 4; ++t) {
            float4 bs = *(const float4*)&wB[(k4 * 4 + t) * H + (j << 2)];
            #pragma unroll
            for (int a = 0; a < 4; ++a) {
                const float va = ((const float*)&xa[a])[t];
                acc[a][0] = fmaf(va, bs.x, acc[a][0]);
                acc[a][1] = fmaf(va, bs.y, acc[a][1]);
                acc[a][2] = fmaf(va, bs.z, acc[a][2]);
                acc[a][3] = fmaf(va, bs.w, acc[a][3]);
            }
        }
    }
    const float4 bv = *(const float4*)&bias[j << 2];
    #pragma unroll
    for (int a = 0; a < 4; ++a) {
        float o[4];
        o[0] = fmaxf(acc[a][0] + bv.x, 0.f);
        o[1] = fmaxf(acc[a][1] + bv.y, 0.f);
        o[2] = fmaxf(acc[a][2] + bv.z, 0.f);
        o[3] = fmaxf(acc[a][3] + bv.w, 0.f);
        ushort4 h4, l4;
        h4.x = f2b(o[0]); l4.x = f2b(o[0] - b2f(h4.x));
        h4.y = f2b(o[1]); l4.y = f2b(o[1] - b2f(h4.y));
        h4.z = f2b(o[2]); l4.z = f2b(o[2] - b2f(h4.z));
        h4.w = f2b(o[3]); l4.w = f2b(o[3] - b2f(h4.w));
        const size_t a0 = (size_t)(row0 + i * 4 + a) * H + (j << 2);
        *(ushort4*)&xh[a0] = h4;
        *(ushort4*)&xl[a0] = l4;
    }
}

// ---------------- CSR build ----------------
__global__ void k_count(const int* __restrict__ ei, const float* __restrict__ emask,
                        int* __restrict__ cnt_i) {
    const int ge = blockIdx.x * 256 + threadIdx.x;
    if (emask[ge] > 0.f) {
        const int b = ge >> 16, e = ge & 0xFFFF;
        const int tgt = ei[(b * 2 + 1) * E + e];
        atomicAdd(&cnt_i[b * N + tgt], 1);
    }
}

__global__ __launch_bounds__(1024) void k_scan(const int* __restrict__ cnt_i,
                                               int* __restrict__ off, int* __restrict__ cur) {
    __shared__ int part[1024];
    const int t = threadIdx.x;
    const int base = t * 64;
    int s = 0;
    for (int u = 0; u < 64; ++u) s += cnt_i[base + u];
    part[t] = s;
    __syncthreads();
    for (int d = 1; d < 1024; d <<= 1) {
        int v = (t >= d) ? part[t - d] : 0;
        __syncthreads();
        part[t] += v;
        __syncthreads();
    }
    int pre = (t == 0) ? 0 : part[t - 1];
    for (int u = 0; u < 64; ++u) {
        const int c = cnt_i[base + u];
        off[base + u] = pre;
        cur[base + u] = pre;
        pre += c;
    }
    if (t == 1023) off[NNODE] = pre;
}

// fill: store source row index and mask value directly (2-deep chain in gather)
__global__ void k_fill(const int* __restrict__ ei, const float* __restrict__ emask,
                       int* __restrict__ cur, int* __restrict__ esrc, float* __restrict__ emv) {
    const int ge = blockIdx.x * 256 + threadIdx.x;
    const float m = emask[ge];
    if (m > 0.f) {
        const int b = ge >> 16, e = ge & 0xFFFF;
        const int tgt = ei[(b * 2 + 1) * E + e];
        const int src = ei[(b * 2) * E + e];
        const int p = atomicAdd(&cur[b * N + tgt], 1);
        esrc[p] = b * N + src;
        emv[p] = m;
    }
}

// ---------------- gather: mean over incoming edges -> split-bf16 ns ----------------
// grid: NNODE blocks x 128 threads; edge list staged in LDS so x-row loads pipeline
__global__ void k_gather2(const unsigned short* __restrict__ xh,
                          const unsigned short* __restrict__ xl,
                          const int* __restrict__ off,
                          const int* __restrict__ esrc, const float* __restrict__ emv,
                          unsigned short* __restrict__ nh, unsigned short* __restrict__ nl) {
    const int r = blockIdx.x;
    const int h = threadIdx.x;
    const int j0 = off[r], j1 = off[r + 1];
    __shared__ int s_src[128];
    __shared__ float s_m[128];
    float acc = 0.f, c = 0.f;
    for (int base = j0; base < j1; base += 128) {
        const int cnt = min(128, j1 - base);
        if (h < cnt) { s_src[h] = esrc[base + h]; s_m[h] = emv[base + h]; }
        __syncthreads();
        #pragma unroll 4
        for (int jj = 0; jj < cnt; ++jj) {
            const size_t a = (size_t)s_src[jj] * H + h;
            const float xv = b2f(xh[a]) + b2f(xl[a]);
            acc = fmaf(xv, s_m[jj], acc);
            c += s_m[jj];
        }
        __syncthreads();
    }
    const float v = acc / fmaxf(c, 1.f);
    const unsigned short hi = f2b(v);
    nh[(size_t)r * H + h] = hi;
    nl[(size_t)r * H + h] = f2b(v - b2f(hi));
}

// ---------------- fused layer: split-bf16 MFMA dual GEMM + bias + relu + LN + mask ----------------
// grid: NNODE/128 = 512 blocks x 256 threads (4 waves). Wave (mw,nw): m-tiles mw*4..+3, n-tiles nw*4..+3.
// In-place on xh/xl: all K-loop reads complete before the epilogue barrier, stores after it.
__global__ __launch_bounds__(256) void k_layer3(const unsigned short* __restrict__ xh,
                                                const unsigned short* __restrict__ xl,
                                                const unsigned short* __restrict__ nh,
                                                const unsigned short* __restrict__ nl,
                                                const unsigned short* __restrict__ Bp,
                                                const float* __restrict__ sb,
                                                const float* __restrict__ nb,
                                                const float* __restrict__ lng,
                                                const float* __restrict__ lnb,
                                                const float* __restrict__ nmask,
                                                unsigned short* __restrict__ oxh,
                                                unsigned short* __restrict__ oxl) {
    const int tid = threadIdx.x;
    const int wave = tid >> 6, lane = tid & 63;
    const int quad = lane >> 4, col = lane & 15;
    const int mw = wave >> 1, nw = wave & 1;
    const int row0 = blockIdx.x * 128;

    f32x4 acc[4][4] = {};

    #pragma unroll 2
    for (int s = 0; s < KSTEPS; ++s) {
        const int g = s >> 2;
        const unsigned short* A = (g == 0 || g == 2) ? xh : (g == 1) ? xl
                                 : (g == 3 || g == 5) ? nh : nl;
        const int koff = (s & 3) * 32 + quad * 8;
        bf16x8 af[4], bf[4];
        #pragma unroll
        for (int mt = 0; mt < 4; ++mt) {
            const int node = row0 + (mw * 4 + mt) * 16 + col;
            af[mt] = *(const bf16x8*)&A[(size_t)node * H + koff];
        }
        #pragma unroll
        for (int nt = 0; nt < 4; ++nt)
            bf[nt] = *(const bf16x8*)&Bp[((size_t)s * 8 + nw * 4 + nt) * 512 + lane * 8];
        #pragma unroll
        for (int mt = 0; mt < 4; ++mt)
            #pragma unroll
            for (int nt = 0; nt < 4; ++nt)
                acc[mt][nt] = __builtin_amdgcn_mfma_f32_16x16x32_bf16(af[mt], bf[nt], acc[mt][nt], 0, 0, 0);
    }

    // bias + relu (C/D layout: row = quad*4 + r, col = lane&15)
    float sbv[4], nbv[4], gv[4], bbv[4];
    #pragma unroll
    for (int nt = 0; nt < 4; ++nt) {
        const int hh = (nw * 4 + nt) * 16 + col;
        sbv[nt] = sb[hh]; nbv[nt] = nb[hh]; gv[nt] = lng[hh]; bbv[nt] = lnb[hh];
    }
    #pragma unroll
    for (int mt = 0; mt < 4; ++mt)
        #pragma unroll
        for (int nt = 0; nt < 4; ++nt)
            #pragma unroll
            for (int r = 0; r < 4; ++r)
                acc[mt][nt][r] = fmaxf(acc[mt][nt][r] + sbv[nt] + nbv[nt], 0.f);

    // LN partials: this wave covers 64 of 128 h; reduce across its 4 n-tiles + 16 lanes
    __shared__ float lsum[2][128];
    __shared__ float lsq[2][128];
    #pragma unroll
    for (int mt = 0; mt < 4; ++mt)
        #pragma unroll
        for (int r = 0; r < 4; ++r) {
            float p = 0.f, q = 0.f;
            #pragma unroll
            for (int nt = 0; nt < 4; ++nt) {
                const float v = acc[mt][nt][r];
                p += v;
                q = fmaf(v, v, q);
            }
            p += __shfl_xor(p, 1);  q += __shfl_xor(q, 1);
            p += __shfl_xor(p, 2);  q += __shfl_xor(q, 2);
            p += __shfl_xor(p, 4);  q += __shfl_xor(q, 4);
            p += __shfl_xor(p, 8);  q += __shfl_xor(q, 8);
            if (col == 0) {
                const int nlidx = (mw * 4 + mt) * 16 + quad * 4 + r;
                lsum[nw][nlidx] = p;
                lsq[nw][nlidx] = q;
            }
        }
    __syncthreads();   // also guarantees all K-loop reads done before in-place stores

    #pragma unroll
    for (int mt = 0; mt < 4; ++mt)
        #pragma unroll
        for (int r = 0; r < 4; ++r) {
            const int nlidx = (mw * 4 + mt) * 16 + quad * 4 + r;
            const int node = row0 + nlidx;
            const float mu = (lsum[0][nlidx] + lsum[1][nlidx]) * (1.f / H);
            const float var = (lsq[0][nlidx] + lsq[1][nlidx]) * (1.f / H) - mu * mu;
            const float isd = rsqrtf(var + EPS);
            const float m = nmask[node];
            #pragma unroll
            for (int nt = 0; nt < 4; ++nt) {
                const float y = (fmaf(acc[mt][nt][r] - mu, isd * gv[nt], bbv[nt])) * m;
                const unsigned short hi = f2b(y);
                const size_t a = (size_t)node * H + (nw * 4 + nt) * 16 + col;
                oxh[a] = hi;
                oxl[a] = f2b(y - b2f(hi));
            }
        }
}

// ---------------- pooling ----------------
__global__ void k_pool1(const unsigned short* __restrict__ xh,
                        const unsigned short* __restrict__ xl,
                        const float* __restrict__ nmask, float* __restrict__ part) {
    const int b = blockIdx.x, c = blockIdx.y, h = threadIdx.x;
    const int n0 = c * PNODES;
    float s = 0.f, mx = -INFINITY, nv = 0.f;
    for (int it = 0; it < PNODES; ++it) {
        const int n = n0 + it;
        const float m = nmask[b * N + n];
        const size_t a = ((size_t)b * N + n) * H + h;
        const float v = (b2f(xh[a]) + b2f(xl[a])) * m;
        s += v;
        if (m > 0.f) mx = fmaxf(mx, v);
        nv += m;
    }
    float* p = part + ((size_t)b * PCHUNK + c) * (2 * H + 1);
    p[h] = s;
    p[H + h] = mx;
    if (h == 0) p[2 * H] = nv;
}

__global__ void k_pool2(const float* __restrict__ part, float* __restrict__ pool) {
    const int b = blockIdx.x, h = threadIdx.x;
    float s = 0.f, mx = -INFINITY, nv = 0.f;
    for (int c = 0; c < PCHUNK; ++c) {
        const float* p = part + ((size_t)b * PCHUNK + c) * (2 * H + 1);
        s += p[h];
        mx = fmaxf(mx, p[H + h]);
        nv += p[2 * H];
    }
    pool[(size_t)b * 2 * H + h] = s / fmaxf(nv, 1.f);
    pool[(size_t)b * 2 * H + H + h] = mx;
}

// ---------------- MLP head ----------------
__global__ void k_head(const float* __restrict__ pool,
                       const float* __restrict__ W1, const float* __restrict__ b1,
                       const float* __restrict__ W2, const float* __restrict__ b2,
                       float* __restrict__ out) {
    const int b = blockIdx.x, t = threadIdx.x;
    __shared__ float g[2 * H];
    __shared__ float hid[H];
    if (t < 2 * H) g[t] = pool[(size_t)b * 2 * H + t];
    __syncthreads();
    if (t < H) {
        float a = b1[t];
        #pragma unroll 8
        for (int k = 0; k < 2 * H; ++k) a = fmaf(g[k], W1[k * H + t], a);
        hid[t] = fmaxf(a, 0.f);
    }
    __syncthreads();
    float a = b2[t];
    #pragma unroll 8
    for (int k = 0; k < H; ++k) a = fmaf(hid[k], W2[k * OUTD + t], a);
    out[(size_t)b * OUTD + t] = a;
}

extern "C" void kernel_launch(void* const* d_in, const int* in_sizes, int n_in,
                              void* d_out, int out_size, void* d_ws, size_t ws_size,
                              hipStream_t stream) {
    const float* feats = (const float*)d_in[0];
    const int*   ei    = (const int*)d_in[1];
    const float* nmask = (const float*)d_in[2];
    const float* emask = (const float*)d_in[3];
    const float* inW   = (const float*)d_in[4];
    const float* inb   = (const float*)d_in[5];
    const float* selfW = (const float*)d_in[6];
    const float* selfb = (const float*)d_in[7];
    const float* neighW= (const float*)d_in[8];
    const float* neighb= (const float*)d_in[9];
    const float* lng   = (const float*)d_in[10];
    const float* lnb   = (const float*)d_in[11];
    const float* W1    = (const float*)d_in[12];
    const float* b1    = (const float*)d_in[13];
    const float* W2    = (const float*)d_in[14];
    const float* b2    = (const float*)d_in[15];
    float* out = (float*)d_out;

    // workspace layout (all regions 16B-aligned)
    const size_t nxh = (size_t)NNODE * H;                 // 8.39M elems
    char* w = (char*)d_ws;
    unsigned short* xh = (unsigned short*)w;  w += nxh * 2;
    unsigned short* xl = (unsigned short*)w;  w += nxh * 2;
    unsigned short* nh = (unsigned short*)w;  w += nxh * 2;
    unsigned short* nl = (unsigned short*)w;  w += nxh * 2;
    unsigned short* Bp = (unsigned short*)w;  w += (size_t)NLAYER * BPL * 2;
    float* part = (float*)w;                  w += (size_t)B * PCHUNK * (2 * H + 1) * 4;
    float* pool = (float*)w;                  w += (size_t)B * 2 * H * 4;
    int* cnt_i  = (int*)w;                    w += (size_t)NNODE * 4;
    int* off    = (int*)w;                    w += ((size_t)NNODE + 4) * 4;
    int* cur    = (int*)w;                    w += (size_t)NNODE * 4;
    int* esrc   = (int*)w;                    w += (size_t)B * E * 4;
    float* emv  = (float*)w;

    k_prepB<<<NLAYER * KSTEPS * 8, 64, 0, stream>>>(selfW, neighW, Bp);
    k_inproj3<<<NNODE / TM, 256, 0, stream>>>(feats, inW, inb, xh, xl);

    hipMemsetAsync(cnt_i, 0, (size_t)NNODE * sizeof(int), stream);
    k_count<<<B * E / 256, 256, 0, stream>>>(ei, emask, cnt_i);
    k_scan<<<1, 1024, 0, stream>>>(cnt_i, off, cur);
    k_fill<<<B * E / 256, 256, 0, stream>>>(ei, emask, cur, esrc, emv);

    for (int l = 0; l < NLAYER; ++l) {
        k_gather2<<<NNODE, H, 0, stream>>>(xh, xl, off, esrc, emv, nh, nl);
        k_layer3<<<NNODE / 128, 256, 0, stream>>>(xh, xl, nh, nl,
                                                  Bp + (size_t)l * BPL,
                                                  selfb + (size_t)l * H, neighb + (size_t)l * H,
                                                  lng + (size_t)l * H, lnb + (size_t)l * H,
                                                  nmask, xh, xl);
    }

    k_pool1<<<dim3(B, PCHUNK), H, 0, stream>>>(xh, xl, nmask, part);
    k_pool2<<<B, H, 0, stream>>>(part, pool);
    k_head<<<B, OUTD, 0, stream>>>(pool, W1, b1, W2, b2, out);
}

// Round 5
// 446.704 us; speedup vs baseline: 3.9207x; 1.0922x over previous
//
#include <hip/hip_runtime.h>
#include <hip/hip_bf16.h>

#define B 8
#define N 8192
#define E 65536
#define FIN 64
#define H 128
#define OUTD 256
#define NLAYER 3
#define EPS 1e-5f
#define PCHUNK 64
#define PNODES (N / PCHUNK)
#define TM 32
#define PADF 68
#define NNODE (B * N)            // 65536 rows
#define KSTEPS 20                // 5 groups x 4 k-steps of K=32
#define BPL (KSTEPS * 8 * 512)   // Bp ushort elems per layer

typedef float f32x4 __attribute__((ext_vector_type(4)));
typedef __bf16 bf16x8 __attribute__((ext_vector_type(8)));

__device__ __forceinline__ float b2f(unsigned short u) {
    union { float f; unsigned int i; } c; c.i = ((unsigned int)u) << 16; return c.f;
}
__device__ __forceinline__ unsigned short f2b(float f) {
    __hip_bfloat16 h = __float2bfloat16(f);          // RTNE
    return *reinterpret_cast<unsigned short*>(&h);
}

// ---------------- weight pre-pack: fragment-ordered split-bf16 B' ----------------
// groups: 0 xh*sWhi, 1 xl*sWhi, 2 xh*sWlo, 3 nh*nWhi, 4 nh*nWlo
__global__ void k_prepB(const float* __restrict__ selfW, const float* __restrict__ neighW,
                        unsigned short* __restrict__ Bp) {
    const int idx = blockIdx.x;            // l*KSTEPS*8 + s*8 + t
    const int t = idx & 7;
    const int s = (idx >> 3) % KSTEPS;
    const int l = idx / (KSTEPS * 8);
    const int lane = threadIdx.x;
    const int quad = lane >> 4, col = lane & 15;
    const int g = s >> 2;
    const float* W = ((g < 3) ? selfW : neighW) + (size_t)l * H * H;
    const bool lo = (g == 2 || g == 4);
    const int n = t * 16 + col;
    unsigned short* dst = Bp + ((size_t)(l * KSTEPS + s) * 8 + t) * 512 + lane * 8;
    #pragma unroll
    for (int j = 0; j < 8; ++j) {
        const int kk = (s & 3) * 32 + quad * 8 + j;
        const float w = W[kk * H + n];
        const unsigned short hi = f2b(w);
        dst[j] = lo ? f2b(w - b2f(hi)) : hi;
    }
}

// ---------------- input projection -> split-bf16 x ----------------
__global__ __launch_bounds__(256) void k_inproj3(const float* __restrict__ feats,
                                                 const float* __restrict__ W,
                                                 const float* __restrict__ bias,
                                                 unsigned short* __restrict__ xh,
                                                 unsigned short* __restrict__ xl) {
    __shared__ float fs[TM * PADF];
    __shared__ float wB[FIN * H];
    const int tid = threadIdx.x;
    const int i = tid >> 5, j = tid & 31;
    const int row0 = blockIdx.x * TM;

    for (int v = tid; v < TM * (FIN / 4); v += 256) {
        int n = v >> 4, kq = (v & 15) << 2;
        *(float4*)&fs[n * PADF + kq] = *(const float4*)&feats[(size_t)(row0 + n) * FIN + kq];
    }
    for (int v = tid; v < FIN * H / 4; v += 256)
        *(float4*)&wB[v * 4] = *(const float4*)&W[v * 4];
    __syncthreads();

    float acc[4][4] = {};
    #pragma unroll
    for (int k4 = 0; k4 < FIN / 4; ++k4) {
        float4 xa[4];
        #pragma unroll
        for (int a = 0; a < 4; ++a)
            xa[a] = *(const float4*)&fs[(i * 4 + a) * PADF + k4 * 4];
        #pragma unroll
        for (int t = 0; t < 4; ++t) {
            float4 bs = *(const float4*)&wB[(k4 * 4 + t) * H + (j << 2)];
            #pragma unroll
            for (int a = 0; a < 4; ++a) {
                const float va = ((const float*)&xa[a])[t];
                acc[a][0] = fmaf(va, bs.x, acc[a][0]);
                acc[a][1] = fmaf(va, bs.y, acc[a][1]);
                acc[a][2] = fmaf(va, bs.z, acc[a][2]);
                acc[a][3] = fmaf(va, bs.w, acc[a][3]);
            }
        }
    }
    const float4 bv = *(const float4*)&bias[j << 2];
    #pragma unroll
    for (int a = 0; a < 4; ++a) {
        float o[4];
        o[0] = fmaxf(acc[a][0] + bv.x, 0.f);
        o[1] = fmaxf(acc[a][1] + bv.y, 0.f);
        o[2] = fmaxf(acc[a][2] + bv.z, 0.f);
        o[3] = fmaxf(acc[a][3] + bv.w, 0.f);
        ushort4 h4, l4;
        h4.x = f2b(o[0]); l4.x = f2b(o[0] - b2f(h4.x));
        h4.y = f2b(o[1]); l4.y = f2b(o[1] - b2f(h4.y));
        h4.z = f2b(o[2]); l4.z = f2b(o[2] - b2f(h4.z));
        h4.w = f2b(o[3]); l4.w = f2b(o[3] - b2f(h4.w));
        const size_t a0 = (size_t)(row0 + i * 4 + a) * H + (j << 2);
        *(ushort4*)&xh[a0] = h4;
        *(ushort4*)&xl[a0] = l4;
    }
}

// ---------------- CSR build ----------------
__global__ void k_count(const int* __restrict__ ei, const float* __restrict__ emask,
                        int* __restrict__ cnt_i) {
    const int ge = blockIdx.x * 256 + threadIdx.x;
    if (emask[ge] > 0.f) {
        const int b = ge >> 16, e = ge & 0xFFFF;
        const int tgt = ei[(b * 2 + 1) * E + e];
        atomicAdd(&cnt_i[b * N + tgt], 1);
    }
}

__global__ __launch_bounds__(1024) void k_scan(const int* __restrict__ cnt_i,
                                               int* __restrict__ off, int* __restrict__ cur) {
    __shared__ int part[1024];
    const int t = threadIdx.x;
    const int base = t * 64;
    int s = 0;
    const int4* c4 = (const int4*)(cnt_i + base);
    #pragma unroll
    for (int u = 0; u < 16; ++u) {
        const int4 v = c4[u];
        s += v.x + v.y + v.z + v.w;
    }
    part[t] = s;
    __syncthreads();
    for (int d = 1; d < 1024; d <<= 1) {
        int v = (t >= d) ? part[t - d] : 0;
        __syncthreads();
        part[t] += v;
        __syncthreads();
    }
    int pre = (t == 0) ? 0 : part[t - 1];
    for (int u = 0; u < 64; ++u) {
        const int c = cnt_i[base + u];
        off[base + u] = pre;
        cur[base + u] = pre;
        pre += c;
    }
    if (t == 1023) off[NNODE] = pre;
}

__global__ void k_fill(const int* __restrict__ ei, const float* __restrict__ emask,
                       int* __restrict__ cur, int* __restrict__ esrc, float* __restrict__ emv) {
    const int ge = blockIdx.x * 256 + threadIdx.x;
    const float m = emask[ge];
    if (m > 0.f) {
        const int b = ge >> 16, e = ge & 0xFFFF;
        const int tgt = ei[(b * 2 + 1) * E + e];
        const int src = ei[(b * 2) * E + e];
        const int p = atomicAdd(&cur[b * N + tgt], 1);
        esrc[p] = b * N + src;
        emv[p] = m;
    }
}

// ---------------- gather: mean over incoming edges, bf16-hi input, wave-per-row ----------------
// XCD swizzle: batch = blockIdx & 7 pins each batch's 2.1 MB xh slice to one XCD's L2.
// Edge idx/mask preloaded to registers, broadcast by __shfl -> all row loads issue independently.
__global__ __launch_bounds__(256) void k_gather3(const unsigned int* __restrict__ xh32,
                                                 const int* __restrict__ off,
                                                 const int* __restrict__ esrc,
                                                 const float* __restrict__ emv,
                                                 unsigned int* __restrict__ nh32) {
    const int beta = blockIdx.x;               // 0..16383
    const int b = beta & 7;
    const int grp = beta >> 3;                 // 0..2047
    const int wave = threadIdx.x >> 6, lane = threadIdx.x & 63;
    const int r = b * N + grp * 4 + wave;
    const int j0 = off[r], j1 = off[r + 1];
    float a0 = 0.f, a1 = 0.f, c = 0.f;
    for (int base = j0; base < j1; base += 64) {
        const int myj = base + lane;
        int s_l = 0; float m_l = 0.f;
        if (myj < j1) { s_l = esrc[myj]; m_l = emv[myj]; }
        const int cnt = min(64, j1 - base);
        #pragma unroll 4
        for (int jj = 0; jj < cnt; ++jj) {
            const int src = __shfl(s_l, jj);
            const float m = __shfl(m_l, jj);
            const unsigned int u = xh32[(size_t)src * 64 + lane];
            union { unsigned int i; float f; } lo, hi;
            lo.i = u << 16;
            hi.i = u & 0xFFFF0000u;
            a0 = fmaf(lo.f, m, a0);
            a1 = fmaf(hi.f, m, a1);
            c += m;
        }
    }
    const float inv = 1.f / fmaxf(c, 1.f);
    nh32[(size_t)r * 64 + lane] = (unsigned int)f2b(a0 * inv) | ((unsigned int)f2b(a1 * inv) << 16);
}

// ---------------- fused layer: split-bf16 MFMA dual GEMM + bias + relu + LN + mask ----------------
__global__ __launch_bounds__(256) void k_layer3(const unsigned short* __restrict__ xh,
                                                const unsigned short* __restrict__ xl,
                                                const unsigned short* __restrict__ nh,
                                                const unsigned short* __restrict__ Bp,
                                                const float* __restrict__ sb,
                                                const float* __restrict__ nb,
                                                const float* __restrict__ lng,
                                                const float* __restrict__ lnb,
                                                const float* __restrict__ nmask,
                                                unsigned short* __restrict__ oxh,
                                                unsigned short* __restrict__ oxl) {
    const int tid = threadIdx.x;
    const int wave = tid >> 6, lane = tid & 63;
    const int quad = lane >> 4, col = lane & 15;
    const int mw = wave >> 1, nw = wave & 1;
    const int row0 = blockIdx.x * 128;

    f32x4 acc[4][4] = {};

    #pragma unroll 2
    for (int s = 0; s < KSTEPS; ++s) {
        const int g = s >> 2;
        const unsigned short* A = (g == 0 || g == 2) ? xh : (g == 1) ? xl : nh;
        const int koff = (s & 3) * 32 + quad * 8;
        bf16x8 af[4], bfr[4];
        #pragma unroll
        for (int mt = 0; mt < 4; ++mt) {
            const int node = row0 + (mw * 4 + mt) * 16 + col;
            af[mt] = *(const bf16x8*)&A[(size_t)node * H + koff];
        }
        #pragma unroll
        for (int nt = 0; nt < 4; ++nt)
            bfr[nt] = *(const bf16x8*)&Bp[((size_t)s * 8 + nw * 4 + nt) * 512 + lane * 8];
        #pragma unroll
        for (int mt = 0; mt < 4; ++mt)
            #pragma unroll
            for (int nt = 0; nt < 4; ++nt)
                acc[mt][nt] = __builtin_amdgcn_mfma_f32_16x16x32_bf16(af[mt], bfr[nt], acc[mt][nt], 0, 0, 0);
    }

    float sbv[4], nbv[4], gv[4], bbv[4];
    #pragma unroll
    for (int nt = 0; nt < 4; ++nt) {
        const int hh = (nw * 4 + nt) * 16 + col;
        sbv[nt] = sb[hh]; nbv[nt] = nb[hh]; gv[nt] = lng[hh]; bbv[nt] = lnb[hh];
    }
    #pragma unroll
    for (int mt = 0; mt < 4; ++mt)
        #pragma unroll
        for (int nt = 0; nt < 4; ++nt)
            #pragma unroll
            for (int r = 0; r < 4; ++r)
                acc[mt][nt][r] = fmaxf(acc[mt][nt][r] + sbv[nt] + nbv[nt], 0.f);

    __shared__ float lsum[2][128];
    __shared__ float lsq[2][128];
    #pragma unroll
    for (int mt = 0; mt < 4; ++mt)
        #pragma unroll
        for (int r = 0; r < 4; ++r) {
            float p = 0.f, q = 0.f;
            #pragma unroll
            for (int nt = 0; nt < 4; ++nt) {
                const float v = acc[mt][nt][r];
                p += v;
                q = fmaf(v, v, q);
            }
            p += __shfl_xor(p, 1);  q += __shfl_xor(q, 1);
            p += __shfl_xor(p, 2);  q += __shfl_xor(q, 2);
            p += __shfl_xor(p, 4);  q += __shfl_xor(q, 4);
            p += __shfl_xor(p, 8);  q += __shfl_xor(q, 8);
            if (col == 0) {
                const int nlidx = (mw * 4 + mt) * 16 + quad * 4 + r;
                lsum[nw][nlidx] = p;
                lsq[nw][nlidx] = q;
            }
        }
    __syncthreads();

    #pragma unroll
    for (int mt = 0; mt < 4; ++mt)
        #pragma unroll
        for (int r = 0; r < 4; ++r) {
            const int nlidx = (mw * 4 + mt) * 16 + quad * 4 + r;
            const int node = row0 + nlidx;
            const float mu = (lsum[0][nlidx] + lsum[1][nlidx]) * (1.f / H);
            const float var = (lsq[0][nlidx] + lsq[1][nlidx]) * (1.f / H) - mu * mu;
            const float isd = rsqrtf(var + EPS);
            const float m = nmask[node];
            #pragma unroll
            for (int nt = 0; nt < 4; ++nt) {
                const float y = (fmaf(acc[mt][nt][r] - mu, isd * gv[nt], bbv[nt])) * m;
                const unsigned short hi = f2b(y);
                const size_t a = (size_t)node * H + (nw * 4 + nt) * 16 + col;
                oxh[a] = hi;
                oxl[a] = f2b(y - b2f(hi));
            }
        }
}

// ---------------- pooling partials ----------------
__global__ void k_pool1(const unsigned short* __restrict__ xh,
                        const unsigned short* __restrict__ xl,
                        const float* __restrict__ nmask, float* __restrict__ part) {
    const int b = blockIdx.x, c = blockIdx.y, h = threadIdx.x;
    const int n0 = c * PNODES;
    float s = 0.f, mx = -INFINITY, nv = 0.f;
    for (int it = 0; it < PNODES; ++it) {
        const int n = n0 + it;
        const float m = nmask[b * N + n];
        const size_t a = ((size_t)b * N + n) * H + h;
        const float v = (b2f(xh[a]) + b2f(xl[a])) * m;
        s += v;
        if (m > 0.f) mx = fmaxf(mx, v);
        nv += m;
    }
    float* p = part + ((size_t)b * PCHUNK + c) * (2 * H + 1);
    p[h] = s;
    p[H + h] = mx;
    if (h == 0) p[2 * H] = nv;
}

// ---------------- fused pool-reduce + MLP head ----------------
__global__ __launch_bounds__(256) void k_tail(const float* __restrict__ part,
                                              const float* __restrict__ W1, const float* __restrict__ b1,
                                              const float* __restrict__ W2, const float* __restrict__ b2,
                                              float* __restrict__ out) {
    const int b = blockIdx.x, t = threadIdx.x;
    __shared__ float g[2 * H];
    __shared__ float hid[H];
    {
        float nv = 0.f;
        for (int c = 0; c < PCHUNK; ++c)
            nv += part[((size_t)b * PCHUNK + c) * (2 * H + 1) + 2 * H];
        if (t < H) {
            float s = 0.f;
            for (int c = 0; c < PCHUNK; ++c)
                s += part[((size_t)b * PCHUNK + c) * (2 * H + 1) + t];
            g[t] = s / fmaxf(nv, 1.f);
        } else {
            const int h = t - H;
            float mx = -INFINITY;
            for (int c = 0; c < PCHUNK; ++c)
                mx = fmaxf(mx, part[((size_t)b * PCHUNK + c) * (2 * H + 1) + H + h]);
            g[t] = mx;
        }
    }
    __syncthreads();
    if (t < H) {
        float a = b1[t];
        #pragma unroll 8
        for (int k = 0; k < 2 * H; ++k) a = fmaf(g[k], W1[k * H + t], a);
        hid[t] = fmaxf(a, 0.f);
    }
    __syncthreads();
    float a = b2[t];
    #pragma unroll 8
    for (int k = 0; k < H; ++k) a = fmaf(hid[k], W2[k * OUTD + t], a);
    out[(size_t)b * OUTD + t] = a;
}

extern "C" void kernel_launch(void* const* d_in, const int* in_sizes, int n_in,
                              void* d_out, int out_size, void* d_ws, size_t ws_size,
                              hipStream_t stream) {
    const float* feats = (const float*)d_in[0];
    const int*   ei    = (const int*)d_in[1];
    const float* nmask = (const float*)d_in[2];
    const float* emask = (const float*)d_in[3];
    const float* inW   = (const float*)d_in[4];
    const float* inb   = (const float*)d_in[5];
    const float* selfW = (const float*)d_in[6];
    const float* selfb = (const float*)d_in[7];
    const float* neighW= (const float*)d_in[8];
    const float* neighb= (const float*)d_in[9];
    const float* lng   = (const float*)d_in[10];
    const float* lnb   = (const float*)d_in[11];
    const float* W1    = (const float*)d_in[12];
    const float* b1    = (const float*)d_in[13];
    const float* W2    = (const float*)d_in[14];
    const float* b2    = (const float*)d_in[15];
    float* out = (float*)d_out;

    const size_t nxh = (size_t)NNODE * H;
    char* w = (char*)d_ws;
    unsigned short* xh = (unsigned short*)w;  w += nxh * 2;
    unsigned short* xl = (unsigned short*)w;  w += nxh * 2;
    unsigned short* nh = (unsigned short*)w;  w += nxh * 2;
    unsigned short* Bp = (unsigned short*)w;  w += (size_t)NLAYER * BPL * 2;
    float* part = (float*)w;                  w += (size_t)B * PCHUNK * (2 * H + 1) * 4;
    int* cnt_i  = (int*)w;                    w += (size_t)NNODE * 4;
    int* off    = (int*)w;                    w += ((size_t)NNODE + 4) * 4;
    int* cur    = (int*)w;                    w += (size_t)NNODE * 4;
    int* esrc   = (int*)w;                    w += (size_t)B * E * 4;
    float* emv  = (float*)w;

    k_prepB<<<NLAYER * KSTEPS * 8, 64, 0, stream>>>(selfW, neighW, Bp);
    k_inproj3<<<NNODE / TM, 256, 0, stream>>>(feats, inW, inb, xh, xl);

    hipMemsetAsync(cnt_i, 0, (size_t)NNODE * sizeof(int), stream);
    k_count<<<B * E / 256, 256, 0, stream>>>(ei, emask, cnt_i);
    k_scan<<<1, 1024, 0, stream>>>(cnt_i, off, cur);
    k_fill<<<B * E / 256, 256, 0, stream>>>(ei, emask, cur, esrc, emv);

    for (int l = 0; l < NLAYER; ++l) {
        k_gather3<<<NNODE / 4, 256, 0, stream>>>((const unsigned int*)xh, off, esrc, emv,
                                                 (unsigned int*)nh);
        k_layer3<<<NNODE / 128, 256, 0, stream>>>(xh, xl, nh,
                                                  Bp + (size_t)l * BPL,
                                                  selfb + (size_t)l * H, neighb + (size_t)l * H,
                                                  lng + (size_t)l * H, lnb + (size_t)l * H,
                                                  nmask, xh, xl);
    }

    k_pool1<<<dim3(B, PCHUNK), H, 0, stream>>>(xh, xl, nmask, part);
    k_tail<<<B, 256, 0, stream>>>(part, W1, b1, W2, b2, out);
}